// Round 10
// baseline (100.942 us; speedup 1.0000x reference)
//
#include <hip/hip_runtime.h>

#define NPART 62
#define M     256
#define DD    256
#define NPOS  8
#define NNEG  248
#define MARG  0.2f
#define REC   512
#define NBLK  496

// ---- ws float-offset layout ----
#define WSP0   (NBLK * REC)          // 62 per-part dist sums
#define CTR0   (WSP0 + 64)           // 62 int part-counters
#define GCTR0  (CTR0 + 62)           // 1 int global counter
#define WS_NEED ((size_t)(GCTR0 + 1) * 4)

#define OFF_HARD 15376
#define OFF_MD   15438
#define OFF_FN   15439

typedef _Float16 f16x8 __attribute__((ext_vector_type(8)));
typedef float    f32x4 __attribute__((ext_vector_type(4)));

#define PITCH 258

// ======================= fully fused kernel =======================
// 496 blocks (8 XCD x 62), 512 threads. Block = (part p, 32-row tile t32).
__global__ __launch_bounds__(512) void k_all(const float* __restrict__ F,
                                             const int* __restrict__ label,
                                             float* __restrict__ ws,
                                             float* __restrict__ out)
{
    // stage: 32KB fragment slab (single-buffered); overlaid later by dist[32][PITCH]
    __shared__ __align__(16) char smem[32 * PITCH * 4];   // 33,024 B
    __shared__ float x2s[M];
    __shared__ float fullS[8][NNEG];
    __shared__ float fullC[8][NNEG];
    __shared__ float posbuf[8][NPOS];
    __shared__ float wred[16];
    __shared__ int flagS, flagG;

    const int bxr  = blockIdx.x;                     // 496 = 8 XCD * 62
    const int swz  = (bxr & 7) * 62 + (bxr >> 3);    // bijective; part's 8 blocks same-XCD
    const int p    = swz >> 3;
    const int t32  = swz & 7;
    const int ib   = t32 * 32;                       // anchor base (global row)
    const int a0   = t32 * 2;                        // first A row-tile (of 16)
    const int t    = threadIdx.x;
    const int lane = t & 63;
    const int w    = t >> 6;                         // wave 0..7

    const float* Fp = F + (size_t)p * (M * DD);

    // staging role: thread t covers (row = t>>1, k-octet pair = t&1) of each 32-k slab
    const int srow  = t >> 1;
    const int sp    = t & 1;                         // octets 2sp, 2sp+1
    const int stile = srow >> 4;
    const float* gsrc = Fp + srow * DD + sp * 16;
    int woff[2][2];                                  // [u][h] half-offsets in stage
#pragma unroll
    for (int u = 0; u < 2; ++u) {
        int o = 2 * sp + u;
        int l = (srow & 15) + 16 * o;
        woff[u][0] = ((stile * 2 + 0) * 64 + l) * 8;
        woff[u][1] = ((stile * 2 + 1) * 64 + l) * 8;
    }

    _Float16* stage = (_Float16*)smem;

    f32x4 acc[2][2];
#pragma unroll
    for (int rt = 0; rt < 2; ++rt)
#pragma unroll
        for (int c = 0; c < 2; ++c) acc[rt][c] = (f32x4){0.f, 0.f, 0.f, 0.f};
    float x2p = 0.f;

    float4 cv0, cv1, cv2, cv3, nv0, nv1, nv2, nv3;

    auto CVTSTORE = [&](float4 a, float4 b, float4 c, float4 d) {
        float xx[16] = {a.x, a.y, a.z, a.w, b.x, b.y, b.z, b.w,
                        c.x, c.y, c.z, c.w, d.x, d.y, d.z, d.w};
#pragma unroll
        for (int u = 0; u < 2; ++u) {
            f16x8 hv, lv;
#pragma unroll
            for (int j = 0; j < 8; ++j) {
                float x = xx[u * 8 + j];
                x2p += x * x;
                _Float16 h = (_Float16)x;
                hv[j] = h;
                lv[j] = (_Float16)(x - (float)h);
            }
            *(f16x8*)(stage + woff[u][0]) = hv;
            *(f16x8*)(stage + woff[u][1]) = lv;
        }
    };

    // prologue: slab 0
    cv0 = *(const float4*)(gsrc + 0);
    cv1 = *(const float4*)(gsrc + 4);
    cv2 = *(const float4*)(gsrc + 8);
    cv3 = *(const float4*)(gsrc + 12);
    CVTSTORE(cv0, cv1, cv2, cv3);
    __syncthreads();

#pragma unroll
    for (int s = 0; s < 8; ++s) {
        if (s < 7) {                                  // issue next-slab loads early (T14)
            nv0 = *(const float4*)(gsrc + (s + 1) * 32 + 0);
            nv1 = *(const float4*)(gsrc + (s + 1) * 32 + 4);
            nv2 = *(const float4*)(gsrc + (s + 1) * 32 + 8);
            nv3 = *(const float4*)(gsrc + (s + 1) * 32 + 12);
        }
        {   // compute slab s: wave w covers col-tiles 2w, 2w+1 x row-tiles a0, a0+1
            f16x8 Bh[2], Bl[2], Ah[2], Al[2];
#pragma unroll
            for (int c = 0; c < 2; ++c) {
                int ct = 2 * w + c;
                Bh[c] = *(const f16x8*)(stage + ((ct * 2 + 0) * 64 + lane) * 8);
                Bl[c] = *(const f16x8*)(stage + ((ct * 2 + 1) * 64 + lane) * 8);
            }
#pragma unroll
            for (int rt = 0; rt < 2; ++rt) {
                Ah[rt] = *(const f16x8*)(stage + (((a0 + rt) * 2 + 0) * 64 + lane) * 8);
                Al[rt] = *(const f16x8*)(stage + (((a0 + rt) * 2 + 1) * 64 + lane) * 8);
            }
#pragma unroll
            for (int rt = 0; rt < 2; ++rt)
#pragma unroll
                for (int c = 0; c < 2; ++c) {
                    acc[rt][c] = __builtin_amdgcn_mfma_f32_16x16x32_f16(Ah[rt], Bh[c], acc[rt][c], 0, 0, 0);
                    acc[rt][c] = __builtin_amdgcn_mfma_f32_16x16x32_f16(Ah[rt], Bl[c], acc[rt][c], 0, 0, 0);
                    acc[rt][c] = __builtin_amdgcn_mfma_f32_16x16x32_f16(Al[rt], Bh[c], acc[rt][c], 0, 0, 0);
                }
        }
        if (s < 7) {
            __syncthreads();                          // all reads of slab s done
            CVTSTORE(nv0, nv1, nv2, nv3);
            __syncthreads();                          // slab s+1 visible
        }
    }

    // ---- x2: pair-reduce (thread t with t^1 shares a row), publish ----
    x2p += __shfl_xor(x2p, 1);
    if (sp == 0) x2s[srow] = x2p;
    __syncthreads();   // x2s ready AND all waves done with stage

    // ---- epilogue: dist -> region (overlays stage) ----
    float* region = (float*)smem;
    const int cbase = lane & 15;
    const int rbase = (lane >> 4) * 4;
#pragma unroll
    for (int rt = 0; rt < 2; ++rt)
#pragma unroll
        for (int c = 0; c < 2; ++c) {
            const float xj = x2s[(2 * w + c) * 16 + cbase];
#pragma unroll
            for (int r = 0; r < 4; ++r) {
                int lrow = rt * 16 + rbase + r;
                float xi = x2s[ib + lrow];
                float d2 = xi + xj - 2.f * acc[rt][c][r];
                region[lrow * PITCH + (2 * w + c) * 16 + cbase] = sqrtf(fmaxf(d2, 0.f) + 1e-12f);
            }
        }
    __syncthreads();

    // ---- mining: wave-private (wave w owns local anchors w*4..w*4+3) ----
    int llab[4];
#pragma unroll
    for (int ch = 0; ch < 4; ++ch) llab[ch] = label[p * M + ch * 64 + lane];

    for (int idx = lane; idx < NNEG; idx += 64) { fullS[w][idx] = 0.f; fullC[w][idx] = 0.f; }

    const unsigned long long lmask = (1ull << lane) - 1ull;
    float hardAcc = 0.f, rowSum = 0.f;

    for (int a = 0; a < 4; ++a) {
        const int ii = w * 4 + a;
        const int li = label[p * M + ib + ii];       // wave-uniform
        int runMatch = 0;
        float negmin = 3.4e38f;
        float ndv[4]; int nqv[4]; int nval[4];
#pragma unroll
        for (int ch = 0; ch < 4; ++ch) {
            const int j = ch * 64 + lane;
            float d = region[ii * PITCH + j];
            bool match = (llab[ch] == li);
            unsigned long long bal = __ballot(match);
            int posRank = runMatch + __popcll(bal & lmask);
            if (match) {
                if (posRank < NPOS) posbuf[w][posRank] = d;
                nval[ch] = 0; ndv[ch] = 0.f; nqv[ch] = 0;
            } else {
                ndv[ch] = d; nqv[ch] = j - posRank; nval[ch] = 1;
                negmin = fminf(negmin, d);
            }
            runMatch += __popcll(bal);
            rowSum += d;
        }
        asm volatile("s_waitcnt lgkmcnt(0)" ::: "memory");  // same-wave posbuf drain

        float maxpos = posbuf[w][0];
#pragma unroll
        for (int pp = 1; pp < NPOS; ++pp) maxpos = fmaxf(maxpos, posbuf[w][pp]);
#pragma unroll
        for (int off = 32; off >= 1; off >>= 1)
            negmin = fminf(negmin, __shfl_xor(negmin, off));
        hardAcc += fmaxf(MARG + maxpos - negmin, 0.f);

#pragma unroll
        for (int ch = 0; ch < 4; ++ch) {
            if (nval[ch]) {
                float dneg = ndv[ch]; int q = nqv[ch];
                float s = 0.f, cnt = 0.f;
#pragma unroll
                for (int pp = 0; pp < NPOS; ++pp) {
                    float v = MARG + posbuf[w][pp] - dneg;
                    if (v > 0.f) { s += v; cnt += 1.f; }
                }
                fullS[w][q] += s;     // per-wave private; q distinct per lane
                fullC[w][q] += cnt;
            }
        }
    }

#pragma unroll
    for (int off = 32; off >= 1; off >>= 1) rowSum += __shfl_xor(rowSum, off);
    if (lane == 0) { wred[w] = hardAcc; wred[8 + w] = rowSum; }
    __syncthreads();

    float* rec = ws + (size_t)swz * REC;
    if (t < NNEG) {
        float s = 0.f, c = 0.f;
#pragma unroll
        for (int v = 0; v < 8; ++v) { s += fullS[v][t]; c += fullC[v][t]; }
        rec[t] = s;
        rec[NNEG + t] = c;
    }
    if (t == 0) {
        float h = 0.f, ds = 0.f;
#pragma unroll
        for (int v = 0; v < 8; ++v) { h += wred[v]; ds += wred[8 + v]; }
        rec[496] = h;
        rec[497] = ds;
    }

    // ---- fused finalize: last of the part's 8 blocks reduces the part ----
    __threadfence();                                  // release my rec stores (all threads)
    __syncthreads();
    if (t == 0) flagS = atomicAdd((int*)(ws + CTR0) + p, 1);
    __syncthreads();
    if (flagS == 7) {                                 // block-uniform branch
        __threadfence();                              // acquire (all threads)
        const float* base = ws + (size_t)(p * 8) * REC;
        if (t < NNEG) {
            float s = 0.f, c = 0.f;
#pragma unroll
            for (int a = 0; a < 8; ++a) {
                s += base[a * REC + t];
                c += base[a * REC + NNEG + t];
            }
            out[p * NNEG + t]          = s / (c + 1e-6f);
            out[OFF_FN + p * NNEG + t] = c;
        }
        if (t == 0) {
            float h = 0.f, ds = 0.f;
#pragma unroll
            for (int a = 0; a < 8; ++a) {
                h  += base[a * REC + 496];
                ds += base[a * REC + 497];
            }
            out[OFF_HARD + p] = h * (1.0f / 256.0f);
            ws[WSP0 + p] = ds;
            __threadfence();                          // release wsP[p]
            flagG = atomicAdd((int*)(ws + GCTR0), 1);
        }
        __syncthreads();
        if (flagG == NPART - 1) {                     // last part-finalizer -> mean_dist
            __threadfence();                          // acquire
            if (t < 64) {
                float v = (t < NPART) ? ws[WSP0 + t] : 0.f;
#pragma unroll
                for (int off = 32; off >= 1; off >>= 1) v += __shfl_xor(v, off);
                if (t == 0) out[OFF_MD] = v / (float)((size_t)NPART * M * M);
            }
        }
    }
}

// ======================= fallback: proven round-1 fused path =======================
__global__ __launch_bounds__(256) void fb_main(
    const float* __restrict__ F, const int* __restrict__ label, float* __restrict__ ws)
{
    __shared__ __align__(16) float region[256 * 36];
    __shared__ float x2s[M];
    __shared__ int   lab[M];
    __shared__ float posbuf[4][NPOS];
    __shared__ float fullS[4][NNEG];
    __shared__ float fullC[4][NNEG];
    __shared__ float wred[8];

    const int bx = blockIdx.x;
    const int p  = bx >> 3;
    const int ib = (bx & 7) * 32;
    const int t  = threadIdx.x;

    lab[t] = label[p * M + t];
    for (int idx = t; idx < 4 * NNEG; idx += 256) {
        (&fullS[0][0])[idx] = 0.f;
        (&fullC[0][0])[idx] = 0.f;
    }
    __syncthreads();

    const float4* Fv = (const float4*)(F + (size_t)p * (M * DD));

    float acc[4][8];
#pragma unroll
    for (int r = 0; r < 4; ++r)
#pragma unroll
        for (int c = 0; c < 8; ++c) acc[r][c] = 0.f;

    float x2loc = 0.f;
    const int tc = t & 31;
    const int tg = t >> 5;

    for (int kt = 0; kt < 8; ++kt) {
#pragma unroll
        for (int w = 0; w < 8; ++w) {
            int ch = w * 256 + t;
            int r  = ch >> 3;
            int q  = ch & 7;
            float4 v = Fv[r * 64 + kt * 8 + q];
            float* dst = &region[r * 36 + q * 4];
            dst[0] = v.x; dst[1] = v.y; dst[2] = v.z; dst[3] = v.w;
        }
        __syncthreads();
#pragma unroll
        for (int k4 = 0; k4 < 8; ++k4) {
            float4 b = *(const float4*)&region[t * 36 + k4 * 4];
            x2loc += b.x * b.x + b.y * b.y + b.z * b.z + b.w * b.w;
        }
#pragma unroll
        for (int k4 = 0; k4 < 8; ++k4) {
            float4 a4[4], b4[8];
#pragma unroll
            for (int r = 0; r < 4; ++r)
                a4[r] = *(const float4*)&region[(ib + tg * 4 + r) * 36 + k4 * 4];
#pragma unroll
            for (int c = 0; c < 8; ++c)
                b4[c] = *(const float4*)&region[(tc + 32 * c) * 36 + k4 * 4];
#pragma unroll
            for (int r = 0; r < 4; ++r)
#pragma unroll
                for (int c = 0; c < 8; ++c)
                    acc[r][c] += a4[r].x * b4[c].x + a4[r].y * b4[c].y +
                                 a4[r].z * b4[c].z + a4[r].w * b4[c].w;
        }
        __syncthreads();
    }

    x2s[t] = x2loc;
    __syncthreads();

#pragma unroll
    for (int r = 0; r < 4; ++r) {
        int ii = tg * 4 + r;
        float xi = x2s[ib + ii];
#pragma unroll
        for (int c = 0; c < 8; ++c) {
            int j = tc + 32 * c;
            float d2 = xi + x2s[j] - 2.f * acc[r][c];
            region[ii * M + j] = sqrtf(fmaxf(d2, 0.f) + 1e-12f);
        }
    }
    __syncthreads();

    const int lane = t & 63;
    const int w    = t >> 6;
    const unsigned long long lmask = (1ull << lane) - 1ull;

    float hardAcc = 0.f;
    float rowSum  = 0.f;

    for (int a = 0; a < 8; ++a) {
        int ii = w * 8 + a;
        int li = lab[ib + ii];
        int runMatch = 0;
        float negmin = 3.4e38f;
        float ndv[4]; int nqv[4]; int nval[4];
#pragma unroll
        for (int ch = 0; ch < 4; ++ch) {
            int j = ch * 64 + lane;
            float d = region[ii * M + j];
            bool match = (lab[j] == li);
            unsigned long long bal = __ballot(match);
            int prefix  = __popcll(bal & lmask);
            int posRank = runMatch + prefix;
            if (match) {
                if (posRank < NPOS) posbuf[w][posRank] = d;
                nval[ch] = 0; ndv[ch] = 0.f; nqv[ch] = 0;
            } else {
                ndv[ch] = d; nqv[ch] = j - posRank; nval[ch] = 1;
                negmin = fminf(negmin, d);
            }
            runMatch += __popcll(bal);
            rowSum += d;
        }
        __syncthreads();

        float maxpos = posbuf[w][0];
#pragma unroll
        for (int pp = 1; pp < NPOS; ++pp) maxpos = fmaxf(maxpos, posbuf[w][pp]);
#pragma unroll
        for (int off = 32; off >= 1; off >>= 1)
            negmin = fminf(negmin, __shfl_xor(negmin, off));
        hardAcc += fmaxf(MARG + maxpos - negmin, 0.f);

#pragma unroll
        for (int ch = 0; ch < 4; ++ch) {
            if (nval[ch]) {
                float dneg = ndv[ch]; int q = nqv[ch];
                float s = 0.f, cnt = 0.f;
#pragma unroll
                for (int pp = 0; pp < NPOS; ++pp) {
                    float v = MARG + posbuf[w][pp] - dneg;
                    if (v > 0.f) { s += v; cnt += 1.f; }
                }
                fullS[w][q] += s;
                fullC[w][q] += cnt;
            }
        }
        __syncthreads();
    }

#pragma unroll
    for (int off = 32; off >= 1; off >>= 1) rowSum += __shfl_xor(rowSum, off);
    if (lane == 0) { wred[w] = hardAcc; wred[4 + w] = rowSum; }
    __syncthreads();

    float* rec = ws + (size_t)bx * REC;
    if (t < NNEG) {
        float s = fullS[0][t] + fullS[1][t] + fullS[2][t] + fullS[3][t];
        float c = fullC[0][t] + fullC[1][t] + fullC[2][t] + fullC[3][t];
        rec[t] = s;
        rec[NNEG + t] = c;
    }
    if (t == 0) {
        rec[496] = wred[0] + wred[1] + wred[2] + wred[3];
        rec[497] = wred[4] + wred[5] + wred[6] + wred[7];
    }
}

__global__ __launch_bounds__(256) void fb_fin1(const float* __restrict__ recs,
                                               float* __restrict__ out,
                                               float* __restrict__ wsP)
{
    const int p = blockIdx.x;
    const int t = threadIdx.x;
    if (t < NNEG) {
        float s = 0.f, c = 0.f;
        for (int a = 0; a < 8; ++a) {
            const float* rec = recs + (size_t)(p * 8 + a) * REC;
            s += rec[t];
            c += rec[NNEG + t];
        }
        out[p * NNEG + t]          = s / (c + 1e-6f);
        out[OFF_FN + p * NNEG + t] = c;
    }
    if (t == 0) {
        float h = 0.f, ds = 0.f;
        for (int a = 0; a < 8; ++a) {
            const float* rec = recs + (size_t)(p * 8 + a) * REC;
            h  += rec[496];
            ds += rec[497];
        }
        out[OFF_HARD + p] = h * (1.0f / 256.0f);
        wsP[p] = ds;
    }
}

__global__ void fb_fin2(const float* __restrict__ wsP, float* __restrict__ out)
{
    int t = threadIdx.x;
    float v = (t < NPART) ? wsP[t] : 0.f;
#pragma unroll
    for (int off = 32; off >= 1; off >>= 1) v += __shfl_xor(v, off);
    if (t == 0) out[OFF_MD] = v / (float)((size_t)NPART * M * M);
}

// ======================= launch =======================
extern "C" void kernel_launch(void* const* d_in, const int* in_sizes, int n_in,
                              void* d_out, int out_size, void* d_ws, size_t ws_size,
                              hipStream_t stream)
{
    const float* F     = (const float*)d_in[0];
    const int*   label = (const int*)d_in[1];
    float*       ws    = (float*)d_ws;
    float*       out   = (float*)d_out;

    if (ws_size >= WS_NEED) {
        // reset the 63 atomic counters (graph-capturable async memset)
        hipMemsetAsync(ws + CTR0, 0, 63 * sizeof(int), stream);
        k_all<<<dim3(NBLK), dim3(512), 0, stream>>>(F, label, ws, out);
    } else {
        float* recs = ws;
        float* wsP  = ws + 496 * REC;
        fb_main<<<dim3(496),   dim3(256), 0, stream>>>(F, label, recs);
        fb_fin1<<<dim3(NPART), dim3(256), 0, stream>>>(recs, out, wsP);
        fb_fin2<<<dim3(1),     dim3(64),  0, stream>>>(wsP, out);
    }
}

// Round 11
// 25.178 us; speedup vs baseline: 4.0091x; 4.0091x over previous
//
#include <hip/hip_runtime.h>

#define NPART 62
#define M     256
#define DD    256
#define NPOS  8
#define NNEG  248
#define MARG  0.2f
#define REC   512

// ---- ws layout (float units): recs + spare ----
#define R0      0
#define WS_NEED ((size_t)(496 * REC) * 4)

#define OFF_HARD 15376
#define OFF_MD   15438
#define OFF_FN   15439

typedef _Float16 f16x8 __attribute__((ext_vector_type(8)));
typedef float    f32x4 __attribute__((ext_vector_type(4)));

#define PITCH 258

// fragment-slot swizzle: position of (row&15, k-octet g) within a 64-entry (tile,h) slab.
// XOR spreads write-side bank slots (row&7) across octets; read side XORs a
// group-uniform constant -> both sides 2-way (free). Bijective.
__device__ __forceinline__ int fragpos(int r15, int g) { return (r15 ^ (g << 1)) + (g << 4); }

// ======================= fused convert + staged MFMA dist + mining =======================
// 248 blocks (8 XCD x 31), 1024 threads. Block = (part p, 64-row tile rt4).
__global__ __launch_bounds__(1024) void k_all(const float* __restrict__ F,
                                              const int* __restrict__ label,
                                              float* __restrict__ recs)
{
    // stage: 2 x 32KB fragment-layout slabs; later overlaid by dist[64][PITCH] (66,048 B)
    __shared__ __align__(16) char smem[64 * PITCH * 4];
    __shared__ float x2s[M];
    __shared__ float fullS[16][NNEG];
    __shared__ float fullC[16][NNEG];
    __shared__ float posbuf[16][NPOS];
    __shared__ float wred[32];

    const int bxr = blockIdx.x;                       // 248 = 8 XCD * 31
    const int swz = (bxr & 7) * 31 + (bxr >> 3);      // bijective; part's 4 tiles same-XCD
    const int p   = swz >> 2;
    const int rt4 = swz & 3;
    const int ib  = rt4 * 64;                         // anchor base (global row)
    const int a0  = rt4 * 4;                          // first A row-tile (of 16)
    const int t   = threadIdx.x;
    const int lane = t & 63;
    const int w    = t >> 6;                          // wave 0..15 = B col-tile

    const float* Fp = F + (size_t)p * (M * DD);

    // staging role: thread t covers (row = t>>2, k-octet = t&3) of each 32-k slab
    const int srow = t >> 2;
    const int soct = t & 3;
    const int stile = srow >> 4;
    const int spos  = fragpos(srow & 15, soct);
    const int whalf_hi = ((stile * 2 + 0) * 64 + spos) * 8;
    const int whalf_lo = ((stile * 2 + 1) * 64 + spos) * 8;
    const float* gsrc = Fp + srow * DD + soct * 8;

    // compute-side fragment lane position (swizzled)
    const int flane = fragpos(lane & 15, lane >> 4);

    _Float16* stage[2] = { (_Float16*)smem, (_Float16*)(smem + 32768) };

    f32x4 acc[4];
#pragma unroll
    for (int rt = 0; rt < 4; ++rt) acc[rt] = (f32x4){0.f, 0.f, 0.f, 0.f};

    float x2p = 0.f;
    float4 v0, v1, n0, n1;

    // prologue: slab 0
    v0 = *(const float4*)(gsrc + 0);
    v1 = *(const float4*)(gsrc + 4);
    {
        float x[8] = {v0.x, v0.y, v0.z, v0.w, v1.x, v1.y, v1.z, v1.w};
        f16x8 hv, lv;
#pragma unroll
        for (int j = 0; j < 8; ++j) {
            x2p += x[j] * x[j];
            _Float16 h = (_Float16)x[j];
            hv[j] = h;
            lv[j] = (_Float16)(x[j] - (float)h);
        }
        *(f16x8*)(stage[0] + whalf_hi) = hv;
        *(f16x8*)(stage[0] + whalf_lo) = lv;
    }
    __syncthreads();

#pragma unroll
    for (int s = 0; s < 8; ++s) {
        if (s < 7) {                                   // issue next-slab loads early (T14)
            n0 = *(const float4*)(gsrc + (s + 1) * 32 + 0);
            n1 = *(const float4*)(gsrc + (s + 1) * 32 + 4);
        }
        // compute slab s from stage[s&1]
        const _Float16* SB = stage[s & 1];
        {
            f16x8 Bh = *(const f16x8*)(SB + ((w * 2 + 0) * 64 + flane) * 8);
            f16x8 Bl = *(const f16x8*)(SB + ((w * 2 + 1) * 64 + flane) * 8);
#pragma unroll
            for (int rt = 0; rt < 4; ++rt) {
                f16x8 Ah = *(const f16x8*)(SB + (((a0 + rt) * 2 + 0) * 64 + flane) * 8);
                f16x8 Al = *(const f16x8*)(SB + (((a0 + rt) * 2 + 1) * 64 + flane) * 8);
                acc[rt] = __builtin_amdgcn_mfma_f32_16x16x32_f16(Ah, Bh, acc[rt], 0, 0, 0);
                acc[rt] = __builtin_amdgcn_mfma_f32_16x16x32_f16(Ah, Bl, acc[rt], 0, 0, 0);
                acc[rt] = __builtin_amdgcn_mfma_f32_16x16x32_f16(Al, Bh, acc[rt], 0, 0, 0);
            }
        }
        if (s < 7) {                                   // convert + write slab s+1 (other buffer)
            float x[8] = {n0.x, n0.y, n0.z, n0.w, n1.x, n1.y, n1.z, n1.w};
            f16x8 hv, lv;
#pragma unroll
            for (int j = 0; j < 8; ++j) {
                x2p += x[j] * x[j];
                _Float16 h = (_Float16)x[j];
                hv[j] = h;
                lv[j] = (_Float16)(x[j] - (float)h);
            }
            _Float16* SW = stage[(s + 1) & 1];
            *(f16x8*)(SW + whalf_hi) = hv;
            *(f16x8*)(SW + whalf_lo) = lv;
            __syncthreads();                           // writes visible before next compute
        }
    }

    // ---- x2: reduce over the 4 octets (lanes differing in bits 0..1), publish ----
    x2p += __shfl_xor(x2p, 1);
    x2p += __shfl_xor(x2p, 2);
    if ((lane & 3) == 0) x2s[srow] = x2p;
    __syncthreads();   // x2s ready AND all waves done with stage buffers

    // ---- epilogue: dist -> LDS region (overlays stage) ----
    float* region = (float*)smem;
    const int cbase = lane & 15;
    const int rbase = (lane >> 4) * 4;
    const float xj = x2s[w * 16 + cbase];
#pragma unroll
    for (int rt = 0; rt < 4; ++rt)
#pragma unroll
        for (int r = 0; r < 4; ++r) {
            float xi = x2s[ib + rt * 16 + rbase + r];
            float d2 = xi + xj - 2.f * acc[rt][r];
            float dd = sqrtf(fmaxf(d2, 0.f) + 1e-12f);
            region[(rt * 16 + rbase + r) * PITCH + w * 16 + cbase] = dd;
        }
    __syncthreads();

    // ---- mining: wave-private (wave w owns local anchors w*4..w*4+3) ----
    int llab[4];
#pragma unroll
    for (int ch = 0; ch < 4; ++ch) llab[ch] = label[p * M + ch * 64 + lane];

    for (int idx = lane; idx < NNEG; idx += 64) { fullS[w][idx] = 0.f; fullC[w][idx] = 0.f; }

    const unsigned long long lmask = (1ull << lane) - 1ull;
    float hardAcc = 0.f, rowSum = 0.f;

    for (int a = 0; a < 4; ++a) {
        const int ii = w * 4 + a;
        const int li = label[p * M + ib + ii];   // wave-uniform
        int runMatch = 0;
        float negmin = 3.4e38f;
        float ndv[4]; int nqv[4]; int nval[4];
#pragma unroll
        for (int ch = 0; ch < 4; ++ch) {
            const int j = ch * 64 + lane;
            float d = region[ii * PITCH + j];
            bool match = (llab[ch] == li);
            unsigned long long bal = __ballot(match);
            int posRank = runMatch + __popcll(bal & lmask);
            if (match) {
                if (posRank < NPOS) posbuf[w][posRank] = d;
                nval[ch] = 0; ndv[ch] = 0.f; nqv[ch] = 0;
            } else {
                ndv[ch] = d; nqv[ch] = j - posRank; nval[ch] = 1;
                negmin = fminf(negmin, d);
            }
            runMatch += __popcll(bal);
            rowSum += d;
        }
        asm volatile("s_waitcnt lgkmcnt(0)" ::: "memory");  // same-wave posbuf drain

        float maxpos = posbuf[w][0];
#pragma unroll
        for (int pp = 1; pp < NPOS; ++pp) maxpos = fmaxf(maxpos, posbuf[w][pp]);
#pragma unroll
        for (int off = 32; off >= 1; off >>= 1)
            negmin = fminf(negmin, __shfl_xor(negmin, off));
        hardAcc += fmaxf(MARG + maxpos - negmin, 0.f);

#pragma unroll
        for (int ch = 0; ch < 4; ++ch) {
            if (nval[ch]) {
                float dneg = ndv[ch]; int q = nqv[ch];
                float s = 0.f, cnt = 0.f;
#pragma unroll
                for (int pp = 0; pp < NPOS; ++pp) {
                    float v = MARG + posbuf[w][pp] - dneg;
                    if (v > 0.f) { s += v; cnt += 1.f; }
                }
                fullS[w][q] += s;   // per-wave private; q distinct per lane
                fullC[w][q] += cnt;
            }
        }
    }

#pragma unroll
    for (int off = 32; off >= 1; off >>= 1) rowSum += __shfl_xor(rowSum, off);
    if (lane == 0) { wred[w] = hardAcc; wred[16 + w] = rowSum; }
    __syncthreads();

    float* rec = recs + (size_t)swz * REC;
    if (t < NNEG) {
        float s = 0.f, c = 0.f;
#pragma unroll
        for (int v = 0; v < 16; ++v) { s += fullS[v][t]; c += fullC[v][t]; }
        rec[t] = s;
        rec[NNEG + t] = c;
    }
    if (t == 0) {
        float h = 0.f, ds = 0.f;
#pragma unroll
        for (int v = 0; v < 16; ++v) { h += wred[v]; ds += wred[16 + v]; }
        rec[496] = h;
        rec[497] = ds;
    }
}

// ======================= merged finalize: 63 blocks =======================
// p < 62: per-part outputs (4 recs). p == 62: mean_dist from all 248 rec[497].
__global__ __launch_bounds__(256) void k_fin(const float* __restrict__ recs,
                                             float* __restrict__ out)
{
    const int p = blockIdx.x;
    const int t = threadIdx.x;
    if (p < NPART) {
        if (t < NNEG) {
            float s = 0.f, c = 0.f;
#pragma unroll
            for (int a = 0; a < 4; ++a) {
                const float* rec = recs + (size_t)(p * 4 + a) * REC;
                s += rec[t];
                c += rec[NNEG + t];
            }
            out[p * NNEG + t]          = s / (c + 1e-6f);
            out[OFF_FN + p * NNEG + t] = c;
        }
        if (t == 0) {
            float h = 0.f;
#pragma unroll
            for (int a = 0; a < 4; ++a) h += recs[(size_t)(p * 4 + a) * REC + 496];
            out[OFF_HARD + p] = h * (1.0f / 256.0f);
        }
    } else {
        __shared__ float red[4];
        float v = (t < 248) ? recs[(size_t)t * REC + 497] : 0.f;
#pragma unroll
        for (int off = 32; off >= 1; off >>= 1) v += __shfl_xor(v, off);
        if ((t & 63) == 0) red[t >> 6] = v;
        __syncthreads();
        if (t == 0)
            out[OFF_MD] = (red[0] + red[1] + red[2] + red[3]) / (float)((size_t)NPART * M * M);
    }
}

// ======================= fallback: proven round-1 fused path =======================
__global__ __launch_bounds__(256) void fb_main(
    const float* __restrict__ F, const int* __restrict__ label, float* __restrict__ ws)
{
    __shared__ __align__(16) float region[256 * 36];
    __shared__ float x2s[M];
    __shared__ int   lab[M];
    __shared__ float posbuf[4][NPOS];
    __shared__ float fullS[4][NNEG];
    __shared__ float fullC[4][NNEG];
    __shared__ float wred[8];

    const int bx = blockIdx.x;
    const int p  = bx >> 3;
    const int ib = (bx & 7) * 32;
    const int t  = threadIdx.x;

    lab[t] = label[p * M + t];
    for (int idx = t; idx < 4 * NNEG; idx += 256) {
        (&fullS[0][0])[idx] = 0.f;
        (&fullC[0][0])[idx] = 0.f;
    }
    __syncthreads();

    const float4* Fv = (const float4*)(F + (size_t)p * (M * DD));

    float acc[4][8];
#pragma unroll
    for (int r = 0; r < 4; ++r)
#pragma unroll
        for (int c = 0; c < 8; ++c) acc[r][c] = 0.f;

    float x2loc = 0.f;
    const int tc = t & 31;
    const int tg = t >> 5;

    for (int kt = 0; kt < 8; ++kt) {
#pragma unroll
        for (int w = 0; w < 8; ++w) {
            int ch = w * 256 + t;
            int r  = ch >> 3;
            int q  = ch & 7;
            float4 v = Fv[r * 64 + kt * 8 + q];
            float* dst = &region[r * 36 + q * 4];
            dst[0] = v.x; dst[1] = v.y; dst[2] = v.z; dst[3] = v.w;
        }
        __syncthreads();
#pragma unroll
        for (int k4 = 0; k4 < 8; ++k4) {
            float4 b = *(const float4*)&region[t * 36 + k4 * 4];
            x2loc += b.x * b.x + b.y * b.y + b.z * b.z + b.w * b.w;
        }
#pragma unroll
        for (int k4 = 0; k4 < 8; ++k4) {
            float4 a4[4], b4[8];
#pragma unroll
            for (int r = 0; r < 4; ++r)
                a4[r] = *(const float4*)&region[(ib + tg * 4 + r) * 36 + k4 * 4];
#pragma unroll
            for (int c = 0; c < 8; ++c)
                b4[c] = *(const float4*)&region[(tc + 32 * c) * 36 + k4 * 4];
#pragma unroll
            for (int r = 0; r < 4; ++r)
#pragma unroll
                for (int c = 0; c < 8; ++c)
                    acc[r][c] += a4[r].x * b4[c].x + a4[r].y * b4[c].y +
                                 a4[r].z * b4[c].z + a4[r].w * b4[c].w;
        }
        __syncthreads();
    }

    x2s[t] = x2loc;
    __syncthreads();

#pragma unroll
    for (int r = 0; r < 4; ++r) {
        int ii = tg * 4 + r;
        float xi = x2s[ib + ii];
#pragma unroll
        for (int c = 0; c < 8; ++c) {
            int j = tc + 32 * c;
            float d2 = xi + x2s[j] - 2.f * acc[r][c];
            region[ii * M + j] = sqrtf(fmaxf(d2, 0.f) + 1e-12f);
        }
    }
    __syncthreads();

    const int lane = t & 63;
    const int w    = t >> 6;
    const unsigned long long lmask = (1ull << lane) - 1ull;

    float hardAcc = 0.f;
    float rowSum  = 0.f;

    for (int a = 0; a < 8; ++a) {
        int ii = w * 8 + a;
        int li = lab[ib + ii];
        int runMatch = 0;
        float negmin = 3.4e38f;
        float ndv[4]; int nqv[4]; int nval[4];
#pragma unroll
        for (int ch = 0; ch < 4; ++ch) {
            int j = ch * 64 + lane;
            float d = region[ii * M + j];
            bool match = (lab[j] == li);
            unsigned long long bal = __ballot(match);
            int prefix  = __popcll(bal & lmask);
            int posRank = runMatch + prefix;
            if (match) {
                if (posRank < NPOS) posbuf[w][posRank] = d;
                nval[ch] = 0; ndv[ch] = 0.f; nqv[ch] = 0;
            } else {
                ndv[ch] = d; nqv[ch] = j - posRank; nval[ch] = 1;
                negmin = fminf(negmin, d);
            }
            runMatch += __popcll(bal);
            rowSum += d;
        }
        __syncthreads();

        float maxpos = posbuf[w][0];
#pragma unroll
        for (int pp = 1; pp < NPOS; ++pp) maxpos = fmaxf(maxpos, posbuf[w][pp]);
#pragma unroll
        for (int off = 32; off >= 1; off >>= 1)
            negmin = fminf(negmin, __shfl_xor(negmin, off));
        hardAcc += fmaxf(MARG + maxpos - negmin, 0.f);

#pragma unroll
        for (int ch = 0; ch < 4; ++ch) {
            if (nval[ch]) {
                float dneg = ndv[ch]; int q = nqv[ch];
                float s = 0.f, cnt = 0.f;
#pragma unroll
                for (int pp = 0; pp < NPOS; ++pp) {
                    float v = MARG + posbuf[w][pp] - dneg;
                    if (v > 0.f) { s += v; cnt += 1.f; }
                }
                fullS[w][q] += s;
                fullC[w][q] += cnt;
            }
        }
        __syncthreads();
    }

#pragma unroll
    for (int off = 32; off >= 1; off >>= 1) rowSum += __shfl_xor(rowSum, off);
    if (lane == 0) { wred[w] = hardAcc; wred[4 + w] = rowSum; }
    __syncthreads();

    float* rec = ws + (size_t)bx * REC;
    if (t < NNEG) {
        float s = fullS[0][t] + fullS[1][t] + fullS[2][t] + fullS[3][t];
        float c = fullC[0][t] + fullC[1][t] + fullC[2][t] + fullC[3][t];
        rec[t] = s;
        rec[NNEG + t] = c;
    }
    if (t == 0) {
        rec[496] = wred[0] + wred[1] + wred[2] + wred[3];
        rec[497] = wred[4] + wred[5] + wred[6] + wred[7];
    }
}

__global__ __launch_bounds__(256) void fb_fin(const float* __restrict__ recs,
                                              float* __restrict__ out)
{
    const int p = blockIdx.x;
    const int t = threadIdx.x;
    if (p < NPART) {
        if (t < NNEG) {
            float s = 0.f, c = 0.f;
            for (int a = 0; a < 8; ++a) {
                const float* rec = recs + (size_t)(p * 8 + a) * REC;
                s += rec[t];
                c += rec[NNEG + t];
            }
            out[p * NNEG + t]          = s / (c + 1e-6f);
            out[OFF_FN + p * NNEG + t] = c;
        }
        if (t == 0) {
            float h = 0.f;
            for (int a = 0; a < 8; ++a) h += recs[(size_t)(p * 8 + a) * REC + 496];
            out[OFF_HARD + p] = h * (1.0f / 256.0f);
        }
    } else {
        __shared__ float red[4];
        float v = 0.f;
        for (int i = t; i < 496; i += 256) v += recs[(size_t)i * REC + 497];
#pragma unroll
        for (int off = 32; off >= 1; off >>= 1) v += __shfl_xor(v, off);
        if ((t & 63) == 0) red[t >> 6] = v;
        __syncthreads();
        if (t == 0)
            out[OFF_MD] = (red[0] + red[1] + red[2] + red[3]) / (float)((size_t)NPART * M * M);
    }
}

// ======================= launch =======================
extern "C" void kernel_launch(void* const* d_in, const int* in_sizes, int n_in,
                              void* d_out, int out_size, void* d_ws, size_t ws_size,
                              hipStream_t stream)
{
    const float* F     = (const float*)d_in[0];
    const int*   label = (const int*)d_in[1];
    float*       ws    = (float*)d_ws;
    float*       out   = (float*)d_out;

    if (ws_size >= WS_NEED) {
        k_all<<<dim3(248), dim3(1024), 0, stream>>>(F, label, ws);
        k_fin<<<dim3(63),  dim3(256),  0, stream>>>(ws, out);
    } else {
        fb_main<<<dim3(496), dim3(256), 0, stream>>>(F, label, ws);
        fb_fin <<<dim3(63),  dim3(256), 0, stream>>>(ws, out);
    }
}